// Round 5
// baseline (416.749 us; speedup 1.0000x reference)
//
#include <hip/hip_runtime.h>
#include <hip/hip_bf16.h>
#include <stdint.h>

// x: [B=16, H=224, W=224, C=64] fp32 NHWC; gating_kernel: [2,2,64,1] fp32
// conv stride 2x2 valid -> g: [16,112,112]; top-K=1254 per batch;
// gate = scatter of top-k values; out = x * gate (broadcast 2x2xC).
#define BATCH   16
#define HDIM    224
#define WDIM    224
#define CDIM    64
#define HO      112
#define WO      112
#define NPATCH  (HO * WO)        // 12544
#define KSEL    1254
#define ROWF    (WDIM * CDIM)    // 14336 floats per image row
#define ROWF4   (WDIM * 16)      // 3584 float4 per image row
#define BLKROW  14               // 3584 / 256 blocks per row in apply

// select kernel geometry: 448 threads (7 waves) x 28 keys = 12544 exactly
#define STH     448
#define SPT     28
#define SWAVES  7
#define CAP     1024             // candidate list capacity

typedef float f32x4 __attribute__((ext_vector_type(4)));

// ---------------------------------------------------------------------------
// Kernel 1: gating conv. One patch per half-wave; 2x128 contiguous floats per
// patch, float4 per lane -> wave-level 1KB contiguous loads. Memory-bound.
// ---------------------------------------------------------------------------
__global__ __launch_bounds__(256) void conv_gate_kernel(
    const float* __restrict__ x, const float* __restrict__ wk,
    float* __restrict__ g) {
  const int tid = threadIdx.x;
  const int lane = tid & 31;
  const int p = blockIdx.x * 8 + (tid >> 5);  // 8 half-waves/block

  const int b   = p / NPATCH;
  const int rem = p - b * NPATCH;
  const int ho  = rem / WO;
  const int wo  = rem - ho * WO;

  const float4 w0 = *reinterpret_cast<const float4*>(wk + lane * 4);
  const float4 w1 = *reinterpret_cast<const float4*>(wk + 128 + lane * 4);

  const long row0 = (long)(b * HDIM + 2 * ho) * ROWF + wo * 128 + lane * 4;
  const float4 a0 = *reinterpret_cast<const float4*>(x + row0);
  const float4 a1 = *reinterpret_cast<const float4*>(x + row0 + ROWF);

  float partial = a0.x * w0.x + a0.y * w0.y + a0.z * w0.z + a0.w * w0.w
                + a1.x * w1.x + a1.y * w1.y + a1.z * w1.z + a1.w * w1.w;

  #pragma unroll
  for (int off = 16; off > 0; off >>= 1)
    partial += __shfl_down(partial, off, 32);

  if (lane == 0) g[p] = partial;
}

// ---------------------------------------------------------------------------
// Kernel 2 (v3): exact per-batch top-K.
//  - bitwise binary search on ONLY the top 16 bits of the order-preserving
//    uint32 key (16 rounds, 1 barrier each, double-buffered wave counts)
//  - candidates in [T, T+2^16) (expected ~26) gathered to LDS; one thread
//    resolves the exact Kth key + stable (lowest-index) ties serially
//  - fallbacks keep exactness for adversarial inputs: block-parallel low-16
//    refinement if candidates > CAP; serial rescan if ties > CAP
// ---------------------------------------------------------------------------
__global__ __launch_bounds__(STH) void select_kernel(
    const float* __restrict__ g, float* __restrict__ gate) {
  __shared__ int cnt[2][SWAVES];
  __shared__ int cand_cnt;
  __shared__ uint32_t cand_key[CAP];
  __shared__ int cand_idx[CAP];
  __shared__ uint8_t used[CAP];
  __shared__ uint32_t sh_T;
  __shared__ int sh_ntie;
  __shared__ int sh_krem;
  __shared__ int sh_over;

  const int b = blockIdx.x, tid = threadIdx.x;
  const float* __restrict__ gb  = g    + b * NPATCH;
  float* __restrict__       gtb = gate + b * NPATCH;

  uint32_t key[SPT];
  #pragma unroll
  for (int j = 0; j < SPT; ++j) {
    uint32_t u = __float_as_uint(gb[tid + j * STH]);
    key[j] = (u & 0x80000000u) ? ~u : (u | 0x80000000u);  // monotone map
  }
  if (tid == 0) { cand_cnt = 0; sh_over = 0; }

  uint32_t T = 0;
  int par = 0;
  // one-barrier block-wide count: every thread gets the total, updates T
  // identically (uniform). Double-buffered cnt -> no second barrier needed.
  auto block_count = [&](int c) -> int {
    #pragma unroll
    for (int off = 32; off > 0; off >>= 1) c += __shfl_down(c, off, 64);
    if ((tid & 63) == 0) cnt[par][tid >> 6] = c;
    __syncthreads();
    int tot = 0;
    #pragma unroll
    for (int wv = 0; wv < SWAVES; ++wv) tot += cnt[par][wv];
    par ^= 1;
    return tot;
  };

  // T = largest 2^16-aligned value with count(key >= T) >= K
  for (int bit = 31; bit >= 16; --bit) {
    const uint32_t c0 = T | (1u << bit);
    int c = 0;
    #pragma unroll
    for (int j = 0; j < SPT; ++j) c += (key[j] >= c0) ? 1 : 0;
    if (block_count(c) >= KSEL) T = c0;
  }

  // cntU = count(key >= T + 2^16)  (invariant guarantees cntU < K)
  int c0n = 0;
  {
    const uint64_t U = (uint64_t)T + 0x10000ull;  // 64-bit: no wrap at top
    #pragma unroll
    for (int j = 0; j < SPT; ++j) c0n += ((uint64_t)key[j] >= U) ? 1 : 0;
  }
  const int cntU = block_count(c0n);
  int krem = KSEL - cntU;       // how many candidates to accept (>=1)

  // gather candidates: keys whose top-16 bits match T's
  #pragma unroll
  for (int j = 0; j < SPT; ++j) {
    if ((key[j] & 0xFFFF0000u) == T) {
      int pos = atomicAdd(&cand_cnt, 1);
      if (pos < CAP) { cand_key[pos] = key[j]; cand_idx[pos] = tid + j * STH; }
    }
  }
  __syncthreads();
  int ncand = cand_cnt;

  if (ncand > CAP) {
    // rare fallback: finish the binary search over the low 16 bits exactly
    for (int bit = 15; bit >= 0; --bit) {
      const uint32_t cc = T | (1u << bit);
      int c = 0;
      #pragma unroll
      for (int j = 0; j < SPT; ++j) c += (key[j] >= cc) ? 1 : 0;
      if (block_count(c) >= KSEL) T = cc;
    }
    int c2 = 0;
    #pragma unroll
    for (int j = 0; j < SPT; ++j) c2 += (key[j] > T) ? 1 : 0;
    const int cg = block_count(c2);
    krem = KSEL - cg;           // ties to keep at exact threshold T
    if (tid == 0) cand_cnt = 0;
    __syncthreads();
    #pragma unroll
    for (int j = 0; j < SPT; ++j) {
      if (key[j] == T) {
        int pos = atomicAdd(&cand_cnt, 1);
        if (pos < CAP) { cand_key[pos] = key[j]; cand_idx[pos] = tid + j * STH; }
      }
    }
    __syncthreads();
    ncand = cand_cnt;
  }

  if (tid == 0) {
    if (ncand <= CAP) {
      // extract krem maxima, stable (lower index wins on equal keys)
      for (int i = 0; i < ncand; ++i) used[i] = 0;
      uint32_t Tx = 0;
      for (int t = 0; t < krem; ++t) {
        int bi = -1; uint32_t bk = 0; int bidx = 0x7FFFFFFF;
        for (int i = 0; i < ncand; ++i) {
          if (used[i]) continue;
          const uint32_t k = cand_key[i];
          if (bi < 0 || k > bk || (k == bk && cand_idx[i] < bidx)) {
            bi = i; bk = k; bidx = cand_idx[i];
          }
        }
        used[bi] = 1; Tx = bk;
      }
      sh_T = Tx;
      int nt = 0;   // compact kept ties in place (nt <= i, safe)
      for (int i = 0; i < ncand; ++i)
        if (used[i] && cand_key[i] == Tx) cand_idx[nt++] = cand_idx[i];
      sh_ntie = nt;
      sh_over = 0;
    } else {
      sh_T = T;       // exact (refinement ran); pathological mass ties
      sh_over = 1;
      sh_krem = krem;
    }
  }
  __syncthreads();
  const uint32_t Tf = sh_T;

  // dense write pass: value if key > Tf else 0 (ties restored after)
  #pragma unroll
  for (int j = 0; j < SPT; ++j) {
    const int i = tid + j * STH;
    const uint32_t k = key[j];
    float v = 0.0f;
    if (k > Tf) {
      uint32_t u = (k & 0x80000000u) ? (k & 0x7FFFFFFFu) : ~k;
      v = __uint_as_float(u);
    }
    gtb[i] = v;
  }
  __syncthreads();

  const float tval =
      __uint_as_float((Tf & 0x80000000u) ? (Tf & 0x7FFFFFFFu) : ~Tf);
  if (!sh_over) {
    for (int i = tid; i < sh_ntie; i += STH) gtb[cand_idx[i]] = tval;
  } else if (tid == 0) {
    int kept = 0; const int kr = sh_krem;
    for (int i = 0; i < NPATCH && kept < kr; ++i) {
      uint32_t u = __float_as_uint(gb[i]);
      uint32_t k = (u & 0x80000000u) ? ~u : (u | 0x80000000u);
      if (k == Tf) { gtb[i] = tval; ++kept; }
    }
  }
}

// ---------------------------------------------------------------------------
// Kernel 3: SPARSE apply. 90% of patches gate==0 -> write zeros without
// reading x. Non-temporal stores for the write-once out stream.
// ---------------------------------------------------------------------------
__global__ __launch_bounds__(256) void apply_gate_kernel(
    const float* __restrict__ x, const float* __restrict__ gate,
    float* __restrict__ out) {
  const int bi = blockIdx.x;
  const int rowblk = bi % BLKROW;
  const int rowid  = bi / BLKROW;          // b*224 + h
  const int h = rowid % HDIM;
  const int b = rowid / HDIM;

  const int v4row = rowblk * 256 + threadIdx.x;
  const int w = v4row >> 4;
  const int gidx = b * NPATCH + (h >> 1) * WO + (w >> 1);

  const float gv = gate[gidx];
  const size_t v4 = (size_t)rowid * ROWF4 + v4row;

  f32x4 o = {0.0f, 0.0f, 0.0f, 0.0f};
  if (gv != 0.0f) {
    const f32x4 a = *reinterpret_cast<const f32x4*>(x + v4 * 4);
    o = a * gv;
  }
  __builtin_nontemporal_store(o, reinterpret_cast<f32x4*>(out + v4 * 4));
}

extern "C" void kernel_launch(void* const* d_in, const int* in_sizes, int n_in,
                              void* d_out, int out_size, void* d_ws, size_t ws_size,
                              hipStream_t stream) {
  const float* x  = (const float*)d_in[0];   // [16,224,224,64]
  const float* wk = (const float*)d_in[1];   // [2,2,64,1]
  float* out = (float*)d_out;

  float* g    = (float*)d_ws;                // [16, 12544]
  float* gate = g + BATCH * NPATCH;          // [16, 12544]

  conv_gate_kernel<<<(BATCH * NPATCH) / 8, 256, 0, stream>>>(x, wk, g);
  select_kernel<<<BATCH, STH, 0, stream>>>(g, gate);
  apply_gate_kernel<<<BATCH * HDIM * BLKROW, 256, 0, stream>>>(x, gate, out);
}

// Round 6
// 353.312 us; speedup vs baseline: 1.1795x; 1.1795x over previous
//
#include <hip/hip_runtime.h>
#include <hip/hip_bf16.h>
#include <stdint.h>

// x: [B=16, H=224, W=224, C=64] fp32 NHWC; gating_kernel: [2,2,64,1] fp32
// conv stride 2x2 valid -> g: [16,112,112]; top-K=1254 per batch;
// gate = scatter of top-k values; out = x * gate (broadcast 2x2xC).
#define BATCH   16
#define HDIM    224
#define WDIM    224
#define CDIM    64
#define HO      112
#define WO      112
#define NPATCH  (HO * WO)        // 12544 = 256 * 49
#define KSEL    1254
#define ROWF    (WDIM * CDIM)    // 14336 floats per image row
#define PERTHR  49               // keys per thread in select
#define ROWF4   (WDIM * 16)      // 3584 float4 per image row
#define BLKROW  14               // 3584 / 256 blocks per row in apply

typedef float f32x4 __attribute__((ext_vector_type(4)));

// ---------------------------------------------------------------------------
// Kernel 1: gating conv. One patch per half-wave; 2x128 contiguous floats per
// patch, float4 per lane -> wave-level 1KB contiguous loads. Memory-bound:
// 205 MB read @ ~6.3 TB/s ~ 33 us floor.  (unchanged from R4)
// ---------------------------------------------------------------------------
__global__ __launch_bounds__(256) void conv_gate_kernel(
    const float* __restrict__ x, const float* __restrict__ wk,
    float* __restrict__ g) {
  const int tid = threadIdx.x;
  const int lane = tid & 31;
  const int p = blockIdx.x * 8 + (tid >> 5);  // 8 half-waves/block

  const int b   = p / NPATCH;
  const int rem = p - b * NPATCH;
  const int ho  = rem / WO;
  const int wo  = rem - ho * WO;

  const float4 w0 = *reinterpret_cast<const float4*>(wk + lane * 4);
  const float4 w1 = *reinterpret_cast<const float4*>(wk + 128 + lane * 4);

  const long row0 = (long)(b * HDIM + 2 * ho) * ROWF + wo * 128 + lane * 4;
  const float4 a0 = *reinterpret_cast<const float4*>(x + row0);
  const float4 a1 = *reinterpret_cast<const float4*>(x + row0 + ROWF);

  float partial = a0.x * w0.x + a0.y * w0.y + a0.z * w0.z + a0.w * w0.w
                + a1.x * w1.x + a1.y * w1.y + a1.z * w1.z + a1.w * w1.w;

  #pragma unroll
  for (int off = 16; off > 0; off >>= 1)
    partial += __shfl_down(partial, off, 32);

  if (lane == 0) g[p] = partial;
}

// ---------------------------------------------------------------------------
// Kernel 2: exact per-batch top-K via 32-step bitwise binary search on
// order-preserving uint32 keys in registers (49/thread, 256 threads).
// R6 change vs proven R4: ONE barrier per count round (double-buffered wave
// counts, every thread sums redundantly -> uniform T update), 34 barriers
// total instead of 66. Tie handling identical to R4 (stable lowest-index).
// ---------------------------------------------------------------------------
__global__ __launch_bounds__(256) void select_kernel(
    const float* __restrict__ g, float* __restrict__ gate) {
  __shared__ int cnt[2][4];
  __shared__ int eq_list[256];
  __shared__ int eq_count;

  const int b = blockIdx.x;
  const int tid = threadIdx.x;
  const float* __restrict__ gb  = g    + b * NPATCH;
  float* __restrict__       gtb = gate + b * NPATCH;

  uint32_t key[PERTHR];
  #pragma unroll
  for (int j = 0; j < PERTHR; ++j) {
    uint32_t u = __float_as_uint(gb[tid + j * 256]);
    key[j] = (u & 0x80000000u) ? ~u : (u | 0x80000000u);  // monotone map
  }
  if (tid == 0) eq_count = 0;

  int par = 0;
  // one-barrier block count: wave-reduce, write cnt[par], barrier, all
  // threads sum the 4 wave totals redundantly (uniform result).
  auto block_count = [&](int c) -> int {
    #pragma unroll
    for (int off = 32; off > 0; off >>= 1) c += __shfl_down(c, off, 64);
    if ((tid & 63) == 0) cnt[par][tid >> 6] = c;
    __syncthreads();
    const int tot = cnt[par][0] + cnt[par][1] + cnt[par][2] + cnt[par][3];
    par ^= 1;
    return tot;
  };

  // T = max{t : count(keys >= t) >= K}, built bit by bit from the top.
  uint32_t T = 0;
  for (int bit = 31; bit >= 0; --bit) {
    const uint32_t cand = T | (1u << bit);
    int c = 0;
    #pragma unroll
    for (int j = 0; j < PERTHR; ++j) c += (key[j] >= cand) ? 1 : 0;
    if (block_count(c) >= KSEL) T = cand;   // uniform across block
  }

  // count strictly-greater -> number of threshold-equal elements to keep
  int cg = 0;
  #pragma unroll
  for (int j = 0; j < PERTHR; ++j) cg += (key[j] > T) ? 1 : 0;
  const int krem = KSEL - block_count(cg);

  // dense write pass; gather threshold-equal indices
  #pragma unroll
  for (int j = 0; j < PERTHR; ++j) {
    const int i = tid + j * 256;
    const uint32_t k = key[j];
    float v = 0.0f;
    if (k > T) {
      uint32_t u = (k & 0x80000000u) ? (k & 0x7FFFFFFFu) : ~k;
      v = __uint_as_float(u);
    }
    gtb[i] = v;
    if (k == T) {
      int pos = atomicAdd(&eq_count, 1);
      if (pos < 256) eq_list[pos] = i;
    }
  }
  __syncthreads();

  if (tid == 0) {
    const int ec = eq_count;
    const float tval =
        __uint_as_float((T & 0x80000000u) ? (T & 0x7FFFFFFFu) : ~T);
    if (ec <= 256) {
      for (int i = 0; i < ec; ++i) {          // sort tiny tie list by index
        int mn = i;
        for (int j = i + 1; j < ec; ++j)
          if (eq_list[j] < eq_list[mn]) mn = j;
        int t = eq_list[mn]; eq_list[mn] = eq_list[i]; eq_list[i] = t;
      }
      for (int i = 0; i < ec && i < krem; ++i)
        gtb[eq_list[i]] = tval;
    } else {
      int kept = 0;                            // pathological mass-tie path
      for (int i = 0; i < NPATCH && kept < krem; ++i) {
        uint32_t u = __float_as_uint(gb[i]);
        uint32_t k = (u & 0x80000000u) ? ~u : (u | 0x80000000u);
        if (k == T) { gtb[i] = tval; ++kept; }
      }
    }
  }
}

// ---------------------------------------------------------------------------
// Kernel 3: SPARSE apply (unchanged from R4). 90% of patches gate==0 ->
// write zeros without reading x (x-read only for selected ~20 MB, L3-hit).
// Non-temporal stores for the write-once out stream. ~205 MB write floor.
// ---------------------------------------------------------------------------
__global__ __launch_bounds__(256) void apply_gate_kernel(
    const float* __restrict__ x, const float* __restrict__ gate,
    float* __restrict__ out) {
  const int bi = blockIdx.x;
  const int rowblk = bi % BLKROW;
  const int rowid  = bi / BLKROW;          // b*224 + h
  const int h = rowid % HDIM;
  const int b = rowid / HDIM;

  const int v4row = rowblk * 256 + threadIdx.x;
  const int w = v4row >> 4;
  const int gidx = b * NPATCH + (h >> 1) * WO + (w >> 1);

  const float gv = gate[gidx];
  const size_t v4 = (size_t)rowid * ROWF4 + v4row;

  f32x4 o = {0.0f, 0.0f, 0.0f, 0.0f};
  if (gv != 0.0f) {
    const f32x4 a = *reinterpret_cast<const f32x4*>(x + v4 * 4);
    o = a * gv;
  }
  __builtin_nontemporal_store(o, reinterpret_cast<f32x4*>(out + v4 * 4));
}

extern "C" void kernel_launch(void* const* d_in, const int* in_sizes, int n_in,
                              void* d_out, int out_size, void* d_ws, size_t ws_size,
                              hipStream_t stream) {
  const float* x  = (const float*)d_in[0];   // [16,224,224,64]
  const float* wk = (const float*)d_in[1];   // [2,2,64,1]
  float* out = (float*)d_out;

  float* g    = (float*)d_ws;                // [16, 12544]
  float* gate = g + BATCH * NPATCH;          // [16, 12544]

  conv_gate_kernel<<<(BATCH * NPATCH) / 8, 256, 0, stream>>>(x, wk, g);
  select_kernel<<<BATCH, 256, 0, stream>>>(g, gate);
  apply_gate_kernel<<<BATCH * HDIM * BLKROW, 256, 0, stream>>>(x, gate, out);
}